// Round 1
// baseline (415.364 us; speedup 1.0000x reference)
//
#include <hip/hip_runtime.h>
#include <hip/hip_bf16.h>

#define H 256
#define SEQ 10

__device__ __forceinline__ float fast_tanh(float x) {
    x = fminf(fmaxf(x, -15.f), 15.f);
    float t = __expf(2.f * x);
    return (t - 1.f) / (t + 1.f);
}

// ent_proj[e][h] = sum_k ent[e][k] * W[k*H + h]   (W0 = rows 0..H-1 of W_attn)
__global__ void ent_proj_kernel(const float* __restrict__ ent,
                                const float* __restrict__ W,
                                float* __restrict__ out, int num_ent) {
    __shared__ float a[32][H];  // 32 KB
    int e0 = blockIdx.x * 32;
    int tid = threadIdx.x;  // 256
    for (int i = tid; i < 32 * H; i += 256) {
        int rrow = i >> 8, c = i & 255;
        int e = e0 + rrow;
        a[rrow][c] = (e < num_ent) ? ent[e * H + c] : 0.f;
    }
    __syncthreads();
    float acc[32];
#pragma unroll
    for (int m = 0; m < 32; m++) acc[m] = 0.f;
    for (int k = 0; k < H; k += 4) {
        float w0 = W[(k + 0) * H + tid];
        float w1 = W[(k + 1) * H + tid];
        float w2 = W[(k + 2) * H + tid];
        float w3 = W[(k + 3) * H + tid];
#pragma unroll
        for (int m = 0; m < 32; m++) {
            float4 av = *reinterpret_cast<const float4*>(&a[m][k]);
            acc[m] += av.x * w0 + av.y * w1 + av.z * w2 + av.w * w3;
        }
    }
    for (int m = 0; m < 32; m++) {
        int e = e0 + m;
        if (e < num_ent) out[e * H + tid] = acc[m];
    }
}

// qpart[q][h] = b[h] + sum_k s_emb[q][k]*W[(H+k)*H+h] + r_emb[q][k]*W[(2H+k)*H+h]
__global__ void qpart_kernel(const int* __restrict__ s, const int* __restrict__ r,
                             const float* __restrict__ ent_embeds,
                             const float* __restrict__ rel_embeds,
                             const float* __restrict__ W,
                             const float* __restrict__ b_attn,
                             float* __restrict__ qpart, int B) {
    __shared__ float as[32][H];
    __shared__ float ar[32][H];  // 64 KB total
    int q0 = blockIdx.x * 32;
    int tid = threadIdx.x;
    for (int i = tid; i < 32 * H; i += 256) {
        int rrow = i >> 8, c = i & 255;
        int q = q0 + rrow;
        if (q < B) {
            as[rrow][c] = ent_embeds[s[q] * H + c];
            ar[rrow][c] = rel_embeds[r[q] * H + c];
        } else {
            as[rrow][c] = 0.f;
            ar[rrow][c] = 0.f;
        }
    }
    __syncthreads();
    float acc[32];
    float bb = b_attn[tid];
#pragma unroll
    for (int m = 0; m < 32; m++) acc[m] = bb;
    for (int k = 0; k < H; k++) {
        float w1 = W[(H + k) * H + tid];
        float w2 = W[(2 * H + k) * H + tid];
#pragma unroll
        for (int m = 0; m < 32; m++) acc[m] += as[m][k] * w1 + ar[m][k] * w2;
    }
    for (int m = 0; m < 32; m++) {
        int q = q0 + m;
        if (q < B) qpart[q * H + tid] = acc[m];
    }
}

// scores[n] = sum_h tanh(ent_proj[nbr[n]][h] + qpart[q][h]) * v_s[h]
// one wave (64 lanes x float4) per neighbor
__global__ void scores_kernel(const int* __restrict__ nbr_ids,
                              const int* __restrict__ seg_ids,
                              const float* __restrict__ ent_proj,
                              const float* __restrict__ qpart,
                              const float* __restrict__ v_s,
                              float* __restrict__ scores, int n) {
    int wid = (blockIdx.x * blockDim.x + threadIdx.x) >> 6;
    int lane = threadIdx.x & 63;
    if (wid >= n) return;
    int nbr = nbr_ids[wid];
    int q = seg_ids[wid] / SEQ;
    float4 a = reinterpret_cast<const float4*>(ent_proj + nbr * H)[lane];
    float4 b = reinterpret_cast<const float4*>(qpart + q * H)[lane];
    float4 v = reinterpret_cast<const float4*>(v_s)[lane];
    float sum = fast_tanh(a.x + b.x) * v.x + fast_tanh(a.y + b.y) * v.y +
                fast_tanh(a.z + b.z) * v.z + fast_tanh(a.w + b.w) * v.w;
#pragma unroll
    for (int off = 32; off; off >>= 1) sum += __shfl_down(sum, off);
    if (lane == 0) scores[wid] = sum;
}

// one block (256 threads) per segment: softmax over segment, weighted agg of
// neighbor embeddings, write full 768-wide output row (zeros if empty).
__global__ void agg_kernel(const int* __restrict__ seg_ids,
                           const int* __restrict__ nbr_ids,
                           const float* __restrict__ scores,
                           const float* __restrict__ ent_embeds,
                           const float* __restrict__ rel_embeds,
                           const int* __restrict__ s, const int* __restrict__ r,
                           float* __restrict__ out, int n) {
    int seg = blockIdx.x;
    int b = seg / SEQ;
    int tid = threadIdx.x;
    __shared__ int sh_range[2];
    if (tid == 0) {
        int lo = 0, hi = n;
        while (lo < hi) { int mid = (lo + hi) >> 1; if (seg_ids[mid] < seg) lo = mid + 1; else hi = mid; }
        sh_range[0] = lo;
        hi = n;
        while (lo < hi) { int mid = (lo + hi) >> 1; if (seg_ids[mid] <= seg) lo = mid + 1; else hi = mid; }
        sh_range[1] = lo;
    }
    __syncthreads();
    int start = sh_range[0], end = sh_range[1];
    float* orow = out + (size_t)seg * (3 * H);
    if (start == end) {
        for (int c = tid; c < 3 * H; c += 256) orow[c] = 0.f;
        return;
    }
    __shared__ float red[256];
    // segment max
    float lmax = -1e30f;
    for (int j = start + tid; j < end; j += 256) lmax = fmaxf(lmax, scores[j]);
    red[tid] = lmax;
    __syncthreads();
    for (int sft = 128; sft; sft >>= 1) {
        if (tid < sft) red[tid] = fmaxf(red[tid], red[tid + sft]);
        __syncthreads();
    }
    float m = red[0];
    __syncthreads();
    // segment denom
    float lsum = 0.f;
    for (int j = start + tid; j < end; j += 256) lsum += __expf(scores[j] - m);
    red[tid] = lsum;
    __syncthreads();
    for (int sft = 128; sft; sft >>= 1) {
        if (tid < sft) red[tid] += red[tid + sft];
        __syncthreads();
    }
    float denom = red[0];
    __syncthreads();
    // weighted aggregate: thread tid owns column tid
    __shared__ float e_sh[256];
    __shared__ int nb_sh[256];
    float acc = 0.f;
    for (int c0 = start; c0 < end; c0 += 256) {
        int j = c0 + tid;
        if (j < end) {
            e_sh[tid] = __expf(scores[j] - m);
            nb_sh[tid] = nbr_ids[j];
        }
        __syncthreads();
        int cc = min(256, end - c0);
        for (int jj = 0; jj < cc; jj++)
            acc += e_sh[jj] * ent_embeds[nb_sh[jj] * H + tid];
        __syncthreads();
    }
    orow[tid] = acc / denom;
    orow[H + tid] = ent_embeds[s[b] * H + tid];
    orow[2 * H + tid] = rel_embeds[r[b] * H + tid];
}

extern "C" void kernel_launch(void* const* d_in, const int* in_sizes, int n_in,
                              void* d_out, int out_size, void* d_ws, size_t ws_size,
                              hipStream_t stream) {
    const int* s = (const int*)d_in[0];
    const int* r = (const int*)d_in[1];
    const int* nbr_ids = (const int*)d_in[2];
    const int* seg_ids = (const int*)d_in[3];
    const float* ent_embeds = (const float*)d_in[4];
    const float* rel_embeds = (const float*)d_in[5];
    const float* W_attn = (const float*)d_in[6];
    const float* b_attn = (const float*)d_in[7];
    const float* v_s = (const float*)d_in[8];
    float* out = (float*)d_out;

    int B = in_sizes[0];
    int N = in_sizes[2];
    int num_ent = in_sizes[4] / H;
    int num_seg = B * SEQ;

    char* ws = (char*)d_ws;
    float* ent_proj = (float*)ws;                       // num_ent*H floats
    float* qpart = ent_proj + (size_t)num_ent * H;      // B*H floats
    float* scores = qpart + (size_t)B * H;              // N floats

    ent_proj_kernel<<<(num_ent + 31) / 32, 256, 0, stream>>>(ent_embeds, W_attn, ent_proj, num_ent);
    qpart_kernel<<<(B + 31) / 32, 256, 0, stream>>>(s, r, ent_embeds, rel_embeds, W_attn, b_attn, qpart, B);
    scores_kernel<<<(N + 3) / 4, 256, 0, stream>>>(nbr_ids, seg_ids, ent_proj, qpart, v_s, scores, N);
    agg_kernel<<<num_seg, 256, 0, stream>>>(seg_ids, nbr_ids, scores, ent_embeds, rel_embeds, s, r, out, N);
}

// Round 2
// 220.688 us; speedup vs baseline: 1.8821x; 1.8821x over previous
//
#include <hip/hip_runtime.h>
#include <hip/hip_bf16.h>

#define H 256
#define SEQ 10

typedef __attribute__((ext_vector_type(8))) short bf16x8;
typedef __attribute__((ext_vector_type(4))) short bf16x4;
typedef __attribute__((ext_vector_type(4))) float f32x4;

__device__ __forceinline__ unsigned short f2bf(float x) {
    union { float f; unsigned u; } v; v.f = x;
    unsigned r = v.u + 0x7fff + ((v.u >> 16) & 1);  // RNE
    return (unsigned short)(r >> 16);
}
__device__ __forceinline__ float bf2f(unsigned short b) {
    union { unsigned u; float f; } v; v.u = ((unsigned)b) << 16;
    return v.f;
}
__device__ __forceinline__ float fast_tanh(float x) {
    x = fminf(fmaxf(x, -15.f), 15.f);
    float t = __expf(2.f * x);
    return (t - 1.f) / (t + 1.f);
}

// f32 -> bf16 bulk convert, 8 elems/thread
__global__ void f32_to_bf16_kernel(const float* __restrict__ in,
                                   unsigned short* __restrict__ out, int n) {
    int i = (blockIdx.x * blockDim.x + threadIdx.x) * 8;
    if (i >= n) return;
    float4 a = *reinterpret_cast<const float4*>(in + i);
    float4 b = *reinterpret_cast<const float4*>(in + i + 4);
    bf16x8 o;
    o[0] = (short)f2bf(a.x); o[1] = (short)f2bf(a.y);
    o[2] = (short)f2bf(a.z); o[3] = (short)f2bf(a.w);
    o[4] = (short)f2bf(b.x); o[5] = (short)f2bf(b.y);
    o[6] = (short)f2bf(b.z); o[7] = (short)f2bf(b.w);
    *reinterpret_cast<bf16x8*>(out + i) = o;
}

// Wt[n][k] = bf16(W_attn[k*H + n]); n in [0,H), k in [0,3H). Row-major [H][3H].
__global__ void prep_Wt_kernel(const float* __restrict__ W,
                               unsigned short* __restrict__ Wt) {
    int idx = blockIdx.x * blockDim.x + threadIdx.x;  // 256*768
    if (idx >= H * 3 * H) return;
    int n = idx / (3 * H), k = idx % (3 * H);
    Wt[idx] = f2bf(W[k * H + n]);
}

// Tiled bf16 MFMA GEMM: out[m][n] = sum_k A[m][k] * Wt[n][k0+k] (+bias[n])
// mode 0: A = Abf (bf16, lda=256). mode 1: A row m = [ent[s[m]] | rel[r[m]]] (f32 gathered).
// Tile 64x64, BK=32, 256 threads = 4 waves, wave w owns cols [w*16, w*16+16).
__global__ void gemm_bf16_kernel(const unsigned short* __restrict__ Abf,
                                 const int* __restrict__ sidx,
                                 const int* __restrict__ ridx,
                                 const float* __restrict__ ent,
                                 const float* __restrict__ rel,
                                 const unsigned short* __restrict__ Wt,
                                 const float* __restrict__ bias,
                                 unsigned short* __restrict__ out,
                                 int M, int K, int k0, int mode) {
    __shared__ unsigned short As[64][40];  // k padded 32->40 (80B rows, 16B-aligned)
    __shared__ unsigned short Bs[64][40];
    int t = threadIdx.x;
    int m0 = blockIdx.x * 64;
    int n0 = blockIdx.y * 64;
    int sr = t >> 2;          // staging row 0..63
    int sc = (t & 3) * 8;     // staging k-elem offset 0/8/16/24
    int wave = t >> 6, lane = t & 63;
    int lr = lane & 15, lg = lane >> 4;

    f32x4 acc[4] = {{0.f, 0.f, 0.f, 0.f}, {0.f, 0.f, 0.f, 0.f},
                    {0.f, 0.f, 0.f, 0.f}, {0.f, 0.f, 0.f, 0.f}};

    for (int kk = 0; kk < K; kk += 32) {
        // stage A
        bf16x8 av = {};
        int gm = m0 + sr;
        if (mode == 0) {
            if (gm < M)
                av = *reinterpret_cast<const bf16x8*>(Abf + (size_t)gm * H + kk + sc);
        } else {
            int k = kk + sc;
            const float* src = (k < H) ? (ent + (size_t)sidx[gm] * H + k)
                                       : (rel + (size_t)ridx[gm] * H + (k - H));
            float4 f0 = *reinterpret_cast<const float4*>(src);
            float4 f1 = *reinterpret_cast<const float4*>(src + 4);
            av[0] = (short)f2bf(f0.x); av[1] = (short)f2bf(f0.y);
            av[2] = (short)f2bf(f0.z); av[3] = (short)f2bf(f0.w);
            av[4] = (short)f2bf(f1.x); av[5] = (short)f2bf(f1.y);
            av[6] = (short)f2bf(f1.z); av[7] = (short)f2bf(f1.w);
        }
        *reinterpret_cast<bf16x8*>(&As[sr][sc]) = av;
        // stage B (Wt rows = output cols)
        bf16x8 bv = *reinterpret_cast<const bf16x8*>(
            Wt + (size_t)(n0 + sr) * (3 * H) + k0 + kk + sc);
        *reinterpret_cast<bf16x8*>(&Bs[sr][sc]) = bv;
        __syncthreads();

        bf16x8 bfr = *reinterpret_cast<const bf16x8*>(&Bs[wave * 16 + lr][lg * 8]);
#pragma unroll
        for (int mf = 0; mf < 4; mf++) {
            bf16x8 afr = *reinterpret_cast<const bf16x8*>(&As[mf * 16 + lr][lg * 8]);
            acc[mf] = __builtin_amdgcn_mfma_f32_16x16x32_bf16(afr, bfr, acc[mf], 0, 0, 0);
        }
        __syncthreads();
    }

    int col = n0 + wave * 16 + lr;
    float bv = bias ? bias[col] : 0.f;
#pragma unroll
    for (int mf = 0; mf < 4; mf++) {
#pragma unroll
        for (int rr = 0; rr < 4; rr++) {
            int row = m0 + mf * 16 + lg * 4 + rr;  // C/D: row=(lane>>4)*4+reg
            if (row < M)
                out[(size_t)row * H + col] = f2bf(acc[mf][rr] + bv);
        }
    }
}

// scores[n] = sum_h tanh(ent_proj[nbr][h] + qpart[q][h]) * v_s[h]
// one wave per neighbor, lane handles 4 cols
__global__ void scores_kernel(const int* __restrict__ nbr_ids,
                              const int* __restrict__ seg_ids,
                              const unsigned short* __restrict__ ent_projbf,
                              const unsigned short* __restrict__ qpartbf,
                              const float* __restrict__ v_s,
                              float* __restrict__ scores, int n) {
    int wid = (blockIdx.x * blockDim.x + threadIdx.x) >> 6;
    int lane = threadIdx.x & 63;
    if (wid >= n) return;
    int nbr = nbr_ids[wid];
    int q = seg_ids[wid] / SEQ;
    bf16x4 a = *reinterpret_cast<const bf16x4*>(ent_projbf + (size_t)nbr * H + lane * 4);
    bf16x4 b = *reinterpret_cast<const bf16x4*>(qpartbf + (size_t)q * H + lane * 4);
    float4 v = reinterpret_cast<const float4*>(v_s)[lane];
    float sum = fast_tanh(bf2f((unsigned short)a[0]) + bf2f((unsigned short)b[0])) * v.x +
                fast_tanh(bf2f((unsigned short)a[1]) + bf2f((unsigned short)b[1])) * v.y +
                fast_tanh(bf2f((unsigned short)a[2]) + bf2f((unsigned short)b[2])) * v.z +
                fast_tanh(bf2f((unsigned short)a[3]) + bf2f((unsigned short)b[3])) * v.w;
#pragma unroll
    for (int off = 32; off; off >>= 1) sum += __shfl_down(sum, off);
    if (lane == 0) scores[wid] = sum;
}

// one block (256 threads) per segment: softmax + weighted agg + write 768-wide row
__global__ void agg_kernel(const int* __restrict__ seg_ids,
                           const int* __restrict__ nbr_ids,
                           const float* __restrict__ scores,
                           const float* __restrict__ ent_embeds,
                           const float* __restrict__ rel_embeds,
                           const int* __restrict__ s, const int* __restrict__ r,
                           float* __restrict__ out, int n) {
    int seg = blockIdx.x;
    int b = seg / SEQ;
    int tid = threadIdx.x;
    __shared__ int sh_range[2];
    if (tid == 0) {
        int lo = 0, hi = n;
        while (lo < hi) { int mid = (lo + hi) >> 1; if (seg_ids[mid] < seg) lo = mid + 1; else hi = mid; }
        sh_range[0] = lo;
        hi = n;
        while (lo < hi) { int mid = (lo + hi) >> 1; if (seg_ids[mid] <= seg) lo = mid + 1; else hi = mid; }
        sh_range[1] = lo;
    }
    __syncthreads();
    int start = sh_range[0], end = sh_range[1];
    float* orow = out + (size_t)seg * (3 * H);
    if (start == end) {
        for (int c = tid; c < 3 * H; c += 256) orow[c] = 0.f;
        return;
    }
    __shared__ float red[256];
    float lmax = -1e30f;
    for (int j = start + tid; j < end; j += 256) lmax = fmaxf(lmax, scores[j]);
    red[tid] = lmax;
    __syncthreads();
    for (int sft = 128; sft; sft >>= 1) {
        if (tid < sft) red[tid] = fmaxf(red[tid], red[tid + sft]);
        __syncthreads();
    }
    float m = red[0];
    __syncthreads();
    float lsum = 0.f;
    for (int j = start + tid; j < end; j += 256) lsum += __expf(scores[j] - m);
    red[tid] = lsum;
    __syncthreads();
    for (int sft = 128; sft; sft >>= 1) {
        if (tid < sft) red[tid] += red[tid + sft];
        __syncthreads();
    }
    float denom = red[0];
    __syncthreads();
    __shared__ float e_sh[256];
    __shared__ int nb_sh[256];
    float acc = 0.f;
    for (int c0 = start; c0 < end; c0 += 256) {
        int j = c0 + tid;
        if (j < end) {
            e_sh[tid] = __expf(scores[j] - m);
            nb_sh[tid] = nbr_ids[j];
        }
        __syncthreads();
        int cc = min(256, end - c0);
        for (int jj = 0; jj < cc; jj++)
            acc += e_sh[jj] * ent_embeds[nb_sh[jj] * H + tid];
        __syncthreads();
    }
    orow[tid] = acc / denom;
    orow[H + tid] = ent_embeds[s[b] * H + tid];
    orow[2 * H + tid] = rel_embeds[r[b] * H + tid];
}

extern "C" void kernel_launch(void* const* d_in, const int* in_sizes, int n_in,
                              void* d_out, int out_size, void* d_ws, size_t ws_size,
                              hipStream_t stream) {
    const int* s = (const int*)d_in[0];
    const int* r = (const int*)d_in[1];
    const int* nbr_ids = (const int*)d_in[2];
    const int* seg_ids = (const int*)d_in[3];
    const float* ent_embeds = (const float*)d_in[4];
    const float* rel_embeds = (const float*)d_in[5];
    const float* W_attn = (const float*)d_in[6];
    const float* b_attn = (const float*)d_in[7];
    const float* v_s = (const float*)d_in[8];
    float* out = (float*)d_out;

    int B = in_sizes[0];
    int N = in_sizes[2];
    int num_ent = in_sizes[4] / H;
    int num_seg = B * SEQ;

    char* ws = (char*)d_ws;
    unsigned short* entbf = (unsigned short*)ws;                    // num_ent*H
    unsigned short* Wt = entbf + (size_t)num_ent * H;               // H*3H
    unsigned short* ent_projbf = Wt + (size_t)H * 3 * H;            // num_ent*H
    unsigned short* qpartbf = ent_projbf + (size_t)num_ent * H;     // B*H
    float* scores = (float*)(qpartbf + (size_t)B * H);              // N

    int n_ent_el = num_ent * H;
    f32_to_bf16_kernel<<<(n_ent_el / 8 + 255) / 256, 256, 0, stream>>>(ent_embeds, entbf, n_ent_el);
    prep_Wt_kernel<<<(H * 3 * H + 255) / 256, 256, 0, stream>>>(W_attn, Wt);

    // ent_proj = entbf @ W0^T(cols)  -> bf16 table
    dim3 g1((num_ent + 63) / 64, H / 64);
    gemm_bf16_kernel<<<g1, 256, 0, stream>>>(entbf, nullptr, nullptr, nullptr, nullptr,
                                             Wt, nullptr, ent_projbf, num_ent, H, 0, 0);
    // qpart = [s_emb|r_emb] @ W12 + b -> bf16 table
    dim3 g2(B / 64, H / 64);
    gemm_bf16_kernel<<<g2, 256, 0, stream>>>(nullptr, s, r, ent_embeds, rel_embeds,
                                             Wt, b_attn, qpartbf, B, 2 * H, H, 1);

    scores_kernel<<<((size_t)N * 64 + 255) / 256, 256, 0, stream>>>(
        nbr_ids, seg_ids, ent_projbf, qpartbf, v_s, scores, N);
    agg_kernel<<<num_seg, 256, 0, stream>>>(seg_ids, nbr_ids, scores, ent_embeds,
                                            rel_embeds, s, r, out, N);
}

// Round 3
// 116.118 us; speedup vs baseline: 3.5771x; 1.9005x over previous
//
#include <hip/hip_runtime.h>
#include <hip/hip_bf16.h>

#define H 256
#define SEQ 10

typedef __attribute__((ext_vector_type(8))) short bf16x8;
typedef __attribute__((ext_vector_type(4))) short bf16x4;
typedef __attribute__((ext_vector_type(4))) float f32x4;

__device__ __forceinline__ unsigned short f2bf(float x) {
    union { float f; unsigned u; } v; v.f = x;
    unsigned r = v.u + 0x7fff + ((v.u >> 16) & 1);  // RNE
    return (unsigned short)(r >> 16);
}
__device__ __forceinline__ float bf2f(unsigned short b) {
    union { unsigned u; float f; } v; v.u = ((unsigned)b) << 16;
    return v.f;
}
__device__ __forceinline__ float fast_tanh(float x) {
    // 1 - 2/(e^2x + 1): exact limits at +-inf, 1 transcendental + 1 rcp
    float t = __expf(2.f * x);
    return 1.f - 2.f * __builtin_amdgcn_rcpf(t + 1.f);
}

// f32 -> bf16 bulk convert, 8 elems/thread
__global__ void f32_to_bf16_kernel(const float* __restrict__ in,
                                   unsigned short* __restrict__ out, int n) {
    int i = (blockIdx.x * blockDim.x + threadIdx.x) * 8;
    if (i >= n) return;
    float4 a = *reinterpret_cast<const float4*>(in + i);
    float4 b = *reinterpret_cast<const float4*>(in + i + 4);
    bf16x8 o;
    o[0] = (short)f2bf(a.x); o[1] = (short)f2bf(a.y);
    o[2] = (short)f2bf(a.z); o[3] = (short)f2bf(a.w);
    o[4] = (short)f2bf(b.x); o[5] = (short)f2bf(b.y);
    o[6] = (short)f2bf(b.z); o[7] = (short)f2bf(b.w);
    *reinterpret_cast<bf16x8*>(out + i) = o;
}

// Wt[n][k] = bf16(W_attn[k*H + n]); row-major [H][3H]
__global__ void prep_Wt_kernel(const float* __restrict__ W,
                               unsigned short* __restrict__ Wt) {
    int idx = blockIdx.x * blockDim.x + threadIdx.x;
    if (idx >= H * 3 * H) return;
    int n = idx / (3 * H), k = idx % (3 * H);
    Wt[idx] = f2bf(W[k * H + n]);
}

// seg_start[s] = lower_bound(seg_ids, s); seg_start[num_seg] = n
__global__ void seg_start_kernel(const int* __restrict__ seg_ids,
                                 int* __restrict__ seg_start, int n, int num_seg) {
    int j = blockIdx.x * blockDim.x + threadIdx.x;
    if (j >= n) return;
    int cur = seg_ids[j];
    int prev = (j == 0) ? -1 : seg_ids[j - 1];
    for (int s2 = prev + 1; s2 <= cur; s2++) seg_start[s2] = j;
    if (j == n - 1)
        for (int s2 = cur + 1; s2 <= num_seg; s2++) seg_start[s2] = n;
}

// Tiled bf16 MFMA GEMM: out[m][n] = sum_k A[m][k] * Wt[n][k0+k] (+bias[n])
// mode 0: A = Abf (bf16, lda=256). mode 1: A row m = [ent[s[m]] | rel[r[m]]].
__global__ void gemm_bf16_kernel(const unsigned short* __restrict__ Abf,
                                 const int* __restrict__ sidx,
                                 const int* __restrict__ ridx,
                                 const float* __restrict__ ent,
                                 const float* __restrict__ rel,
                                 const unsigned short* __restrict__ Wt,
                                 const float* __restrict__ bias,
                                 unsigned short* __restrict__ out,
                                 int M, int K, int k0, int mode) {
    __shared__ unsigned short As[64][40];
    __shared__ unsigned short Bs[64][40];
    int t = threadIdx.x;
    int m0 = blockIdx.x * 64;
    int n0 = blockIdx.y * 64;
    int sr = t >> 2;
    int sc = (t & 3) * 8;
    int wave = t >> 6, lane = t & 63;
    int lr = lane & 15, lg = lane >> 4;

    f32x4 acc[4] = {{0.f, 0.f, 0.f, 0.f}, {0.f, 0.f, 0.f, 0.f},
                    {0.f, 0.f, 0.f, 0.f}, {0.f, 0.f, 0.f, 0.f}};

    for (int kk = 0; kk < K; kk += 32) {
        bf16x8 av = {};
        int gm = m0 + sr;
        if (mode == 0) {
            if (gm < M)
                av = *reinterpret_cast<const bf16x8*>(Abf + (size_t)gm * H + kk + sc);
        } else {
            int k = kk + sc;
            const float* src = (k < H) ? (ent + (size_t)sidx[gm] * H + k)
                                       : (rel + (size_t)ridx[gm] * H + (k - H));
            float4 f0 = *reinterpret_cast<const float4*>(src);
            float4 f1 = *reinterpret_cast<const float4*>(src + 4);
            av[0] = (short)f2bf(f0.x); av[1] = (short)f2bf(f0.y);
            av[2] = (short)f2bf(f0.z); av[3] = (short)f2bf(f0.w);
            av[4] = (short)f2bf(f1.x); av[5] = (short)f2bf(f1.y);
            av[6] = (short)f2bf(f1.z); av[7] = (short)f2bf(f1.w);
        }
        *reinterpret_cast<bf16x8*>(&As[sr][sc]) = av;
        bf16x8 bv = *reinterpret_cast<const bf16x8*>(
            Wt + (size_t)(n0 + sr) * (3 * H) + k0 + kk + sc);
        *reinterpret_cast<bf16x8*>(&Bs[sr][sc]) = bv;
        __syncthreads();

        bf16x8 bfr = *reinterpret_cast<const bf16x8*>(&Bs[wave * 16 + lr][lg * 8]);
#pragma unroll
        for (int mf = 0; mf < 4; mf++) {
            bf16x8 afr = *reinterpret_cast<const bf16x8*>(&As[mf * 16 + lr][lg * 8]);
            acc[mf] = __builtin_amdgcn_mfma_f32_16x16x32_bf16(afr, bfr, acc[mf], 0, 0, 0);
        }
        __syncthreads();
    }

    int col = n0 + wave * 16 + lr;
    float bv = bias ? bias[col] : 0.f;
#pragma unroll
    for (int mf = 0; mf < 4; mf++) {
#pragma unroll
        for (int rr = 0; rr < 4; rr++) {
            int row = m0 + mf * 16 + lg * 4 + rr;
            if (row < M)
                out[(size_t)row * H + col] = f2bf(acc[mf][rr] + bv);
        }
    }
}

// One wave per segment: fused score + online-softmax + weighted aggregate +
// full 768-wide output row write (zeros for empty segments).
__global__ void fused_agg_kernel(const int* __restrict__ nbr_ids,
                                 const int* __restrict__ seg_start,
                                 const unsigned short* __restrict__ projbf,
                                 const unsigned short* __restrict__ entbf,
                                 const unsigned short* __restrict__ qpartbf,
                                 const float* __restrict__ v_s,
                                 const float* __restrict__ ent_embeds,
                                 const float* __restrict__ rel_embeds,
                                 const int* __restrict__ s,
                                 const int* __restrict__ r,
                                 float* __restrict__ out, int num_seg) {
    int seg = blockIdx.x * 4 + (threadIdx.x >> 6);
    if (seg >= num_seg) return;
    int lane = threadIdx.x & 63;
    int b = seg / SEQ;
    int start = seg_start[seg], end = seg_start[seg + 1];
    float* orow = out + (size_t)seg * (3 * H);
    int c4 = lane * 4;

    if (start == end) {
        float4 z = {0.f, 0.f, 0.f, 0.f};
        *reinterpret_cast<float4*>(orow + c4) = z;
        *reinterpret_cast<float4*>(orow + H + c4) = z;
        *reinterpret_cast<float4*>(orow + 2 * H + c4) = z;
        return;
    }

    bf16x4 qp = *reinterpret_cast<const bf16x4*>(qpartbf + (size_t)b * H + c4);
    float q0 = bf2f((unsigned short)qp[0]), q1 = bf2f((unsigned short)qp[1]);
    float q2 = bf2f((unsigned short)qp[2]), q3 = bf2f((unsigned short)qp[3]);
    float4 v = *reinterpret_cast<const float4*>(v_s + c4);

    float m = -1e30f, l = 0.f;
    float4 acc = {0.f, 0.f, 0.f, 0.f};

    int nbr = nbr_ids[start];
    bf16x4 pa = *reinterpret_cast<const bf16x4*>(projbf + (size_t)nbr * H + c4);
    bf16x4 em = *reinterpret_cast<const bf16x4*>(entbf + (size_t)nbr * H + c4);

    for (int j = start; j < end; j++) {
        bf16x4 pa_n = {}, em_n = {};
        if (j + 1 < end) {  // prefetch next neighbor's rows
            int nb2 = nbr_ids[j + 1];
            pa_n = *reinterpret_cast<const bf16x4*>(projbf + (size_t)nb2 * H + c4);
            em_n = *reinterpret_cast<const bf16x4*>(entbf + (size_t)nb2 * H + c4);
        }
        float sp = fast_tanh(bf2f((unsigned short)pa[0]) + q0) * v.x +
                   fast_tanh(bf2f((unsigned short)pa[1]) + q1) * v.y +
                   fast_tanh(bf2f((unsigned short)pa[2]) + q2) * v.z +
                   fast_tanh(bf2f((unsigned short)pa[3]) + q3) * v.w;
#pragma unroll
        for (int off = 1; off < 64; off <<= 1) sp += __shfl_xor(sp, off);
        float newm = fmaxf(m, sp);
        float scale = __expf(m - newm);
        float e = __expf(sp - newm);
        l = l * scale + e;
        acc.x = acc.x * scale + e * bf2f((unsigned short)em[0]);
        acc.y = acc.y * scale + e * bf2f((unsigned short)em[1]);
        acc.z = acc.z * scale + e * bf2f((unsigned short)em[2]);
        acc.w = acc.w * scale + e * bf2f((unsigned short)em[3]);
        m = newm;
        pa = pa_n;
        em = em_n;
    }

    float invl = 1.f / l;
    float4 o0 = {acc.x * invl, acc.y * invl, acc.z * invl, acc.w * invl};
    *reinterpret_cast<float4*>(orow + c4) = o0;
    *reinterpret_cast<float4*>(orow + H + c4) =
        *reinterpret_cast<const float4*>(ent_embeds + (size_t)s[b] * H + c4);
    *reinterpret_cast<float4*>(orow + 2 * H + c4) =
        *reinterpret_cast<const float4*>(rel_embeds + (size_t)r[b] * H + c4);
}

extern "C" void kernel_launch(void* const* d_in, const int* in_sizes, int n_in,
                              void* d_out, int out_size, void* d_ws, size_t ws_size,
                              hipStream_t stream) {
    const int* s = (const int*)d_in[0];
    const int* r = (const int*)d_in[1];
    const int* nbr_ids = (const int*)d_in[2];
    const int* seg_ids = (const int*)d_in[3];
    const float* ent_embeds = (const float*)d_in[4];
    const float* rel_embeds = (const float*)d_in[5];
    const float* W_attn = (const float*)d_in[6];
    const float* b_attn = (const float*)d_in[7];
    const float* v_s = (const float*)d_in[8];
    float* out = (float*)d_out;

    int B = in_sizes[0];
    int N = in_sizes[2];
    int num_ent = in_sizes[4] / H;
    int num_seg = B * SEQ;

    char* ws = (char*)d_ws;
    unsigned short* entbf = (unsigned short*)ws;                    // num_ent*H
    unsigned short* Wt = entbf + (size_t)num_ent * H;               // H*3H
    unsigned short* projbf = Wt + (size_t)H * 3 * H;                // num_ent*H
    unsigned short* qpartbf = projbf + (size_t)num_ent * H;         // B*H
    int* seg_start = (int*)(qpartbf + (size_t)B * H);               // num_seg+1

    int n_ent_el = num_ent * H;
    f32_to_bf16_kernel<<<(n_ent_el / 8 + 255) / 256, 256, 0, stream>>>(ent_embeds, entbf, n_ent_el);
    prep_Wt_kernel<<<(H * 3 * H + 255) / 256, 256, 0, stream>>>(W_attn, Wt);
    seg_start_kernel<<<(N + 255) / 256, 256, 0, stream>>>(seg_ids, seg_start, N, num_seg);

    dim3 g1((num_ent + 63) / 64, H / 64);
    gemm_bf16_kernel<<<g1, 256, 0, stream>>>(entbf, nullptr, nullptr, nullptr, nullptr,
                                             Wt, nullptr, projbf, num_ent, H, 0, 0);
    dim3 g2(B / 64, H / 64);
    gemm_bf16_kernel<<<g2, 256, 0, stream>>>(nullptr, s, r, ent_embeds, rel_embeds,
                                             Wt, b_attn, qpartbf, B, 2 * H, H, 1);

    fused_agg_kernel<<<(num_seg + 3) / 4, 256, 0, stream>>>(
        nbr_ids, seg_start, projbf, entbf, qpartbf, v_s,
        ent_embeds, rel_embeds, s, r, out, num_seg);
}

// Round 4
// 105.442 us; speedup vs baseline: 3.9393x; 1.1013x over previous
//
#include <hip/hip_runtime.h>
#include <hip/hip_bf16.h>

#define H 256
#define SEQ 10

typedef __attribute__((ext_vector_type(8))) short bf16x8;
typedef __attribute__((ext_vector_type(4))) short bf16x4;
typedef __attribute__((ext_vector_type(4))) float f32x4;

__device__ __forceinline__ unsigned short f2bf(float x) {
    union { float f; unsigned u; } v; v.f = x;
    unsigned r = v.u + 0x7fff + ((v.u >> 16) & 1);  // RNE
    return (unsigned short)(r >> 16);
}
__device__ __forceinline__ float bf2f(unsigned short b) {
    union { unsigned u; float f; } v; v.u = ((unsigned)b) << 16;
    return v.f;
}
__device__ __forceinline__ float fast_tanh(float x) {
    float t = __expf(2.f * x);
    return 1.f - 2.f * __builtin_amdgcn_rcpf(t + 1.f);
}

// write em half of combined table: comb[e][256+i] = bf16(ent[e][i])
__global__ void conv_ent_kernel(const float* __restrict__ ent,
                                unsigned short* __restrict__ comb, int n) {
    int g0 = (blockIdx.x * blockDim.x + threadIdx.x) * 8;
    if (g0 >= n) return;
    float4 a = *reinterpret_cast<const float4*>(ent + g0);
    float4 b = *reinterpret_cast<const float4*>(ent + g0 + 4);
    bf16x8 o;
    o[0] = (short)f2bf(a.x); o[1] = (short)f2bf(a.y);
    o[2] = (short)f2bf(a.z); o[3] = (short)f2bf(a.w);
    o[4] = (short)f2bf(b.x); o[5] = (short)f2bf(b.y);
    o[6] = (short)f2bf(b.z); o[7] = (short)f2bf(b.w);
    int e = g0 >> 8, i = g0 & 255;
    *reinterpret_cast<bf16x8*>(comb + (size_t)e * 512 + 256 + i) = o;
}

// Wt[n][k] = bf16(W_attn[k*H + n]); row-major [H][3H]
__global__ void prep_Wt_kernel(const float* __restrict__ W,
                               unsigned short* __restrict__ Wt) {
    int idx = blockIdx.x * blockDim.x + threadIdx.x;
    if (idx >= H * 3 * H) return;
    int n = idx / (3 * H), k = idx % (3 * H);
    Wt[idx] = f2bf(W[k * H + n]);
}

// seg_start[s] = lower_bound(seg_ids, s); seg_start[num_seg] = n
__global__ void seg_start_kernel(const int* __restrict__ seg_ids,
                                 int* __restrict__ seg_start, int n, int num_seg) {
    int j = blockIdx.x * blockDim.x + threadIdx.x;
    if (j >= n) return;
    int cur = seg_ids[j];
    int prev = (j == 0) ? -1 : seg_ids[j - 1];
    for (int s2 = prev + 1; s2 <= cur; s2++) seg_start[s2] = j;
    if (j == n - 1)
        for (int s2 = cur + 1; s2 <= num_seg; s2++) seg_start[s2] = n;
}

// Tiled bf16 MFMA GEMM: out[m][n] = sum_k A[m][k] * Wt[n][k0+k] (+bias[n])
// mode 0: A = Abf (bf16, stride lda). mode 1: A row m = [ent[s[m]] | rel[r[m]]].
__global__ void gemm_bf16_kernel(const unsigned short* __restrict__ Abf,
                                 const int* __restrict__ sidx,
                                 const int* __restrict__ ridx,
                                 const float* __restrict__ ent,
                                 const float* __restrict__ rel,
                                 const unsigned short* __restrict__ Wt,
                                 const float* __restrict__ bias,
                                 unsigned short* __restrict__ out,
                                 int M, int K, int k0, int mode, int lda, int ldo) {
    __shared__ unsigned short As[64][40];
    __shared__ unsigned short Bs[64][40];
    int t = threadIdx.x;
    int m0 = blockIdx.x * 64;
    int n0 = blockIdx.y * 64;
    int sr = t >> 2;
    int sc = (t & 3) * 8;
    int wave = t >> 6, lane = t & 63;
    int lr = lane & 15, lg = lane >> 4;

    f32x4 acc[4] = {{0.f, 0.f, 0.f, 0.f}, {0.f, 0.f, 0.f, 0.f},
                    {0.f, 0.f, 0.f, 0.f}, {0.f, 0.f, 0.f, 0.f}};

    for (int kk = 0; kk < K; kk += 32) {
        bf16x8 av = {};
        int gm = m0 + sr;
        if (mode == 0) {
            if (gm < M)
                av = *reinterpret_cast<const bf16x8*>(Abf + (size_t)gm * lda + kk + sc);
        } else {
            int k = kk + sc;
            const float* src = (k < H) ? (ent + (size_t)sidx[gm] * H + k)
                                       : (rel + (size_t)ridx[gm] * H + (k - H));
            float4 f0 = *reinterpret_cast<const float4*>(src);
            float4 f1 = *reinterpret_cast<const float4*>(src + 4);
            av[0] = (short)f2bf(f0.x); av[1] = (short)f2bf(f0.y);
            av[2] = (short)f2bf(f0.z); av[3] = (short)f2bf(f0.w);
            av[4] = (short)f2bf(f1.x); av[5] = (short)f2bf(f1.y);
            av[6] = (short)f2bf(f1.z); av[7] = (short)f2bf(f1.w);
        }
        *reinterpret_cast<bf16x8*>(&As[sr][sc]) = av;
        bf16x8 bv = *reinterpret_cast<const bf16x8*>(
            Wt + (size_t)(n0 + sr) * (3 * H) + k0 + kk + sc);
        *reinterpret_cast<bf16x8*>(&Bs[sr][sc]) = bv;
        __syncthreads();

        bf16x8 bfr = *reinterpret_cast<const bf16x8*>(&Bs[wave * 16 + lr][lg * 8]);
#pragma unroll
        for (int mf = 0; mf < 4; mf++) {
            bf16x8 afr = *reinterpret_cast<const bf16x8*>(&As[mf * 16 + lr][lg * 8]);
            acc[mf] = __builtin_amdgcn_mfma_f32_16x16x32_bf16(afr, bfr, acc[mf], 0, 0, 0);
        }
        __syncthreads();
    }

    int col = n0 + wave * 16 + lr;
    float bv = bias ? bias[col] : 0.f;
#pragma unroll
    for (int mf = 0; mf < 4; mf++) {
#pragma unroll
        for (int rr = 0; rr < 4; rr++) {
            int row = m0 + mf * 16 + lg * 4 + rr;
            if (row < M)
                out[(size_t)row * ldo + col] = f2bf(acc[mf][rr] + bv);
        }
    }
}

// One wave per segment, single pass, no max-subtraction (|score| <= ~10.2).
// Lane group g (16 lanes) handles neighbors j == 4*ji+g; lane covers 16 cols.
__global__ void fused_agg_kernel(const int* __restrict__ nbr_ids,
                                 const int* __restrict__ seg_start,
                                 const unsigned short* __restrict__ comb,
                                 const unsigned short* __restrict__ qpartbf,
                                 const float* __restrict__ v_s,
                                 const float* __restrict__ ent_embeds,
                                 const float* __restrict__ rel_embeds,
                                 const int* __restrict__ s,
                                 const int* __restrict__ r,
                                 float* __restrict__ out, int num_seg) {
    int seg = blockIdx.x * 4 + (threadIdx.x >> 6);
    if (seg >= num_seg) return;
    int lane = threadIdx.x & 63;
    int b = seg / SEQ;
    int start = seg_start[seg], end = seg_start[seg + 1];
    float* orow = out + (size_t)seg * (3 * H);
    int c4 = lane * 4;

    if (start == end) {
        float4 z = {0.f, 0.f, 0.f, 0.f};
        *reinterpret_cast<float4*>(orow + c4) = z;
        *reinterpret_cast<float4*>(orow + H + c4) = z;
        *reinterpret_cast<float4*>(orow + 2 * H + c4) = z;
        return;
    }

    int g = lane >> 4, li = lane & 15;
    int cb = li * 16;

    float qv[16], vv[16];
    {
        bf16x8 qa = *reinterpret_cast<const bf16x8*>(qpartbf + (size_t)b * H + cb);
        bf16x8 qb = *reinterpret_cast<const bf16x8*>(qpartbf + (size_t)b * H + cb + 8);
#pragma unroll
        for (int k = 0; k < 8; k++) {
            qv[k] = bf2f((unsigned short)qa[k]);
            qv[8 + k] = bf2f((unsigned short)qb[k]);
        }
        const float4* vp = reinterpret_cast<const float4*>(v_s + cb);
#pragma unroll
        for (int k = 0; k < 4; k++) {
            float4 tv = vp[k];
            vv[4 * k + 0] = tv.x; vv[4 * k + 1] = tv.y;
            vv[4 * k + 2] = tv.z; vv[4 * k + 3] = tv.w;
        }
    }

    float acc[16];
#pragma unroll
    for (int k = 0; k < 16; k++) acc[k] = 0.f;
    float lpart = 0.f;

    int cc = end - start;
    int nitm = (cc + 3) >> 2;
    for (int ji = 0; ji < nitm; ji++) {
        int j = 4 * ji + g;
        if (j < cc) {
            int nbr = nbr_ids[start + j];
            const unsigned short* row = comb + (size_t)nbr * 512 + cb;
            bf16x8 p0 = *reinterpret_cast<const bf16x8*>(row);
            bf16x8 p1 = *reinterpret_cast<const bf16x8*>(row + 8);
            bf16x8 e0 = *reinterpret_cast<const bf16x8*>(row + 256);
            bf16x8 e1 = *reinterpret_cast<const bf16x8*>(row + 264);
            float s16 = 0.f;
#pragma unroll
            for (int k = 0; k < 8; k++) {
                s16 += fast_tanh(bf2f((unsigned short)p0[k]) + qv[k]) * vv[k];
                s16 += fast_tanh(bf2f((unsigned short)p1[k]) + qv[8 + k]) * vv[8 + k];
            }
            s16 += __shfl_xor(s16, 1);
            s16 += __shfl_xor(s16, 2);
            s16 += __shfl_xor(s16, 4);
            s16 += __shfl_xor(s16, 8);
            float e = __expf(s16);
            lpart += e;
#pragma unroll
            for (int k = 0; k < 8; k++) {
                acc[k] += e * bf2f((unsigned short)e0[k]);
                acc[8 + k] += e * bf2f((unsigned short)e1[k]);
            }
        }
    }

    // combine the 4 lane-groups
    lpart += __shfl_xor(lpart, 16);
    lpart += __shfl_xor(lpart, 32);
#pragma unroll
    for (int k = 0; k < 16; k++) {
        acc[k] += __shfl_xor(acc[k], 16);
        acc[k] += __shfl_xor(acc[k], 32);
    }
    float invl = 1.f / lpart;

    // lane (g,li) writes cols cb + 4g .. cb + 4g+3 (static selects, no dyn index)
    float4 o;
#pragma unroll
    for (int k = 0; k < 4; k++) {
        float v0 = acc[k], v1 = acc[4 + k], v2 = acc[8 + k], v3 = acc[12 + k];
        float pick = (g == 0) ? v0 : (g == 1) ? v1 : (g == 2) ? v2 : v3;
        if (k == 0) o.x = pick * invl;
        else if (k == 1) o.y = pick * invl;
        else if (k == 2) o.z = pick * invl;
        else o.w = pick * invl;
    }
    *reinterpret_cast<float4*>(orow + cb + 4 * g) = o;
    *reinterpret_cast<float4*>(orow + H + c4) =
        *reinterpret_cast<const float4*>(ent_embeds + (size_t)s[b] * H + c4);
    *reinterpret_cast<float4*>(orow + 2 * H + c4) =
        *reinterpret_cast<const float4*>(rel_embeds + (size_t)r[b] * H + c4);
}

extern "C" void kernel_launch(void* const* d_in, const int* in_sizes, int n_in,
                              void* d_out, int out_size, void* d_ws, size_t ws_size,
                              hipStream_t stream) {
    const int* s = (const int*)d_in[0];
    const int* r = (const int*)d_in[1];
    const int* nbr_ids = (const int*)d_in[2];
    const int* seg_ids = (const int*)d_in[3];
    const float* ent_embeds = (const float*)d_in[4];
    const float* rel_embeds = (const float*)d_in[5];
    const float* W_attn = (const float*)d_in[6];
    const float* b_attn = (const float*)d_in[7];
    const float* v_s = (const float*)d_in[8];
    float* out = (float*)d_out;

    int B = in_sizes[0];
    int N = in_sizes[2];
    int num_ent = in_sizes[4] / H;
    int num_seg = B * SEQ;

    char* ws = (char*)d_ws;
    unsigned short* comb = (unsigned short*)ws;                 // num_ent*512 (proj|em)
    unsigned short* Wt = comb + (size_t)num_ent * 512;          // H*3H
    unsigned short* qpartbf = Wt + (size_t)H * 3 * H;           // B*H
    int* seg_start = (int*)(qpartbf + (size_t)B * H);           // num_seg+1

    int n_ent_el = num_ent * H;
    conv_ent_kernel<<<(n_ent_el / 8 + 255) / 256, 256, 0, stream>>>(ent_embeds, comb, n_ent_el);
    prep_Wt_kernel<<<(H * 3 * H + 255) / 256, 256, 0, stream>>>(W_attn, Wt);
    seg_start_kernel<<<(N + 255) / 256, 256, 0, stream>>>(seg_ids, seg_start, N, num_seg);

    // proj half of comb = em(bf16) @ W0 cols, A read from comb's em half (lda=512)
    dim3 g1((num_ent + 63) / 64, H / 64);
    gemm_bf16_kernel<<<g1, 256, 0, stream>>>(comb + 256, nullptr, nullptr, nullptr, nullptr,
                                             Wt, nullptr, comb, num_ent, H, 0, 0, 512, 512);
    // qpart = [s_emb|r_emb] @ W12 + b
    dim3 g2(B / 64, H / 64);
    gemm_bf16_kernel<<<g2, 256, 0, stream>>>(nullptr, s, r, ent_embeds, rel_embeds,
                                             Wt, b_attn, qpartbf, B, 2 * H, H, 1, 0, H);

    fused_agg_kernel<<<(num_seg + 3) / 4, 256, 0, stream>>>(
        nbr_ids, seg_start, comb, qpartbf, v_s,
        ent_embeds, rel_embeds, s, r, out, num_seg);
}

// Round 5
// 103.912 us; speedup vs baseline: 3.9972x; 1.0147x over previous
//
#include <hip/hip_runtime.h>
#include <hip/hip_bf16.h>

#define H 256
#define SEQ 10

typedef __attribute__((ext_vector_type(8))) short bf16x8;
typedef __attribute__((ext_vector_type(4))) short bf16x4;
typedef __attribute__((ext_vector_type(4))) float f32x4;

__device__ __forceinline__ unsigned short f2bf(float x) {
    union { float f; unsigned u; } v; v.f = x;
    unsigned r = v.u + 0x7fff + ((v.u >> 16) & 1);  // RNE
    return (unsigned short)(r >> 16);
}
__device__ __forceinline__ float bf2f(unsigned short b) {
    union { unsigned u; float f; } v; v.u = ((unsigned)b) << 16;
    return v.f;
}
__device__ __forceinline__ float fexp2(float x) {
    return __builtin_amdgcn_exp2f(x);
}
// tanh(x) = 1 - 2/(exp2(x*2*log2e) + 1)
__device__ __forceinline__ float fast_tanh(float x) {
    float t = fexp2(x * 2.885390082f);
    return 1.f - 2.f * __builtin_amdgcn_rcpf(t + 1.f);
}

// Wt[n][k] = bf16(W_attn[k*H + n]); row-major [H][3H]
__global__ void prep_Wt_kernel(const float* __restrict__ W,
                               unsigned short* __restrict__ Wt) {
    int idx = blockIdx.x * blockDim.x + threadIdx.x;
    if (idx >= H * 3 * H) return;
    int n = idx / (3 * H), k = idx % (3 * H);
    Wt[idx] = f2bf(W[k * H + n]);
}

// seg_start[s] = lower_bound(seg_ids, s); seg_start[num_seg] = n
__global__ void seg_start_kernel(const int* __restrict__ seg_ids,
                                 int* __restrict__ seg_start, int n, int num_seg) {
    int j = blockIdx.x * blockDim.x + threadIdx.x;
    if (j >= n) return;
    int cur = seg_ids[j];
    int prev = (j == 0) ? -1 : seg_ids[j - 1];
    for (int s2 = prev + 1; s2 <= cur; s2++) seg_start[s2] = j;
    if (j == n - 1)
        for (int s2 = cur + 1; s2 <= num_seg; s2++) seg_start[s2] = n;
}

// Tiled bf16 MFMA GEMM: out[m][n] = sum_k A[m][k] * Wt[n][k0+k] (+bias[n])
// mode 0: A = entf (f32, convert in staging); blocks with n0==0 also write the
//         staged bf16 A row into em_out (comb em half, stride 512, offset 256).
// mode 1: A row m = [ent[s[m]] | rel[r[m]]] (f32 gathered).
__global__ void gemm_bf16_kernel(const float* __restrict__ entf,
                                 const int* __restrict__ sidx,
                                 const int* __restrict__ ridx,
                                 const float* __restrict__ ent,
                                 const float* __restrict__ rel,
                                 const unsigned short* __restrict__ Wt,
                                 const float* __restrict__ bias,
                                 unsigned short* __restrict__ out,
                                 unsigned short* __restrict__ em_out,
                                 int M, int K, int k0, int mode, int ldo) {
    __shared__ unsigned short As[64][40];
    __shared__ unsigned short Bs[64][40];
    int t = threadIdx.x;
    int m0 = blockIdx.x * 64;
    int n0 = blockIdx.y * 64;
    int sr = t >> 2;
    int sc = (t & 3) * 8;
    int wave = t >> 6, lane = t & 63;
    int lr = lane & 15, lg = lane >> 4;

    f32x4 acc[4] = {{0.f, 0.f, 0.f, 0.f}, {0.f, 0.f, 0.f, 0.f},
                    {0.f, 0.f, 0.f, 0.f}, {0.f, 0.f, 0.f, 0.f}};

    for (int kk = 0; kk < K; kk += 32) {
        bf16x8 av = {};
        int gm = m0 + sr;
        if (gm < M) {
            const float* src;
            if (mode == 0) {
                src = entf + (size_t)gm * H + kk + sc;
            } else {
                int k = kk + sc;
                src = (k < H) ? (ent + (size_t)sidx[gm] * H + k)
                              : (rel + (size_t)ridx[gm] * H + (k - H));
            }
            float4 f0 = *reinterpret_cast<const float4*>(src);
            float4 f1 = *reinterpret_cast<const float4*>(src + 4);
            av[0] = (short)f2bf(f0.x); av[1] = (short)f2bf(f0.y);
            av[2] = (short)f2bf(f0.z); av[3] = (short)f2bf(f0.w);
            av[4] = (short)f2bf(f1.x); av[5] = (short)f2bf(f1.y);
            av[6] = (short)f2bf(f1.z); av[7] = (short)f2bf(f1.w);
            if (mode == 0 && em_out && n0 == 0)
                *reinterpret_cast<bf16x8*>(em_out + (size_t)gm * 512 + 256 + kk + sc) = av;
        }
        *reinterpret_cast<bf16x8*>(&As[sr][sc]) = av;
        bf16x8 bv = *reinterpret_cast<const bf16x8*>(
            Wt + (size_t)(n0 + sr) * (3 * H) + k0 + kk + sc);
        *reinterpret_cast<bf16x8*>(&Bs[sr][sc]) = bv;
        __syncthreads();

        bf16x8 bfr = *reinterpret_cast<const bf16x8*>(&Bs[wave * 16 + lr][lg * 8]);
#pragma unroll
        for (int mf = 0; mf < 4; mf++) {
            bf16x8 afr = *reinterpret_cast<const bf16x8*>(&As[mf * 16 + lr][lg * 8]);
            acc[mf] = __builtin_amdgcn_mfma_f32_16x16x32_bf16(afr, bfr, acc[mf], 0, 0, 0);
        }
        __syncthreads();
    }

    int col = n0 + wave * 16 + lr;
    float bv = bias ? bias[col] : 0.f;
#pragma unroll
    for (int mf = 0; mf < 4; mf++) {
#pragma unroll
        for (int rr = 0; rr < 4; rr++) {
            int row = m0 + mf * 16 + lg * 4 + rr;
            if (row < M)
                out[(size_t)row * ldo + col] = f2bf(acc[mf][rr] + bv);
        }
    }
}

// One wave per segment, 2 waves per block. Single pass, no max-subtraction
// (|score| <= sum|v| ~ 10.2, safe in f32). Lane group g (16 lanes) handles
// neighbors j == 4*ji+g; each lane covers 16 contiguous cols.
__global__ void __launch_bounds__(128)
fused_agg_kernel(const int* __restrict__ nbr_ids,
                 const int* __restrict__ seg_start,
                 const unsigned short* __restrict__ comb,
                 const unsigned short* __restrict__ qpartbf,
                 const float* __restrict__ v_s,
                 const float* __restrict__ ent_embeds,
                 const float* __restrict__ rel_embeds,
                 const int* __restrict__ s,
                 const int* __restrict__ r,
                 float* __restrict__ out, int num_seg) {
    int seg = blockIdx.x * 2 + (threadIdx.x >> 6);
    if (seg >= num_seg) return;
    int lane = threadIdx.x & 63;
    int b = seg / SEQ;
    int start = seg_start[seg], end = seg_start[seg + 1];
    float* orow = out + (size_t)seg * (3 * H);
    int c4 = lane * 4;

    if (start == end) {
        float4 z = {0.f, 0.f, 0.f, 0.f};
        *reinterpret_cast<float4*>(orow + c4) = z;
        *reinterpret_cast<float4*>(orow + H + c4) = z;
        *reinterpret_cast<float4*>(orow + 2 * H + c4) = z;
        return;
    }

    int g = lane >> 4, li = lane & 15;
    int cb = li * 16;

    float qv[16], vv[16];
    {
        bf16x8 qa = *reinterpret_cast<const bf16x8*>(qpartbf + (size_t)b * H + cb);
        bf16x8 qb = *reinterpret_cast<const bf16x8*>(qpartbf + (size_t)b * H + cb + 8);
#pragma unroll
        for (int k = 0; k < 8; k++) {
            qv[k] = bf2f((unsigned short)qa[k]);
            qv[8 + k] = bf2f((unsigned short)qb[k]);
        }
        const float4* vp = reinterpret_cast<const float4*>(v_s + cb);
#pragma unroll
        for (int k = 0; k < 4; k++) {
            float4 tv = vp[k];
            vv[4 * k + 0] = tv.x; vv[4 * k + 1] = tv.y;
            vv[4 * k + 2] = tv.z; vv[4 * k + 3] = tv.w;
        }
    }

    float acc[16];
#pragma unroll
    for (int k = 0; k < 16; k++) acc[k] = 0.f;
    float lpart = 0.f;

    int cc = end - start;
    int nitm = (cc + 3) >> 2;

    // software pipeline, 1-deep; indices clamped so loads are unconditional
    int j0 = min(g, cc - 1);
    const unsigned short* row = comb + (size_t)nbr_ids[start + j0] * 512 + cb;
    bf16x8 p0 = *reinterpret_cast<const bf16x8*>(row);
    bf16x8 p1 = *reinterpret_cast<const bf16x8*>(row + 8);
    bf16x8 e0 = *reinterpret_cast<const bf16x8*>(row + 256);
    bf16x8 e1 = *reinterpret_cast<const bf16x8*>(row + 264);

    for (int ji = 0; ji < nitm; ji++) {
        int jn = min(4 * (ji + 1) + g, cc - 1);
        const unsigned short* rown = comb + (size_t)nbr_ids[start + jn] * 512 + cb;
        bf16x8 p0n = *reinterpret_cast<const bf16x8*>(rown);
        bf16x8 p1n = *reinterpret_cast<const bf16x8*>(rown + 8);
        bf16x8 e0n = *reinterpret_cast<const bf16x8*>(rown + 256);
        bf16x8 e1n = *reinterpret_cast<const bf16x8*>(rown + 264);

        float s16 = 0.f;
#pragma unroll
        for (int k = 0; k < 8; k++) {
            s16 += fast_tanh(bf2f((unsigned short)p0[k]) + qv[k]) * vv[k];
            s16 += fast_tanh(bf2f((unsigned short)p1[k]) + qv[8 + k]) * vv[8 + k];
        }
        s16 += __shfl_xor(s16, 1);
        s16 += __shfl_xor(s16, 2);
        s16 += __shfl_xor(s16, 4);
        s16 += __shfl_xor(s16, 8);
        float e = fexp2(s16 * 1.4426950408889634f);
        e = (4 * ji + g < cc) ? e : 0.f;
        lpart += e;
#pragma unroll
        for (int k = 0; k < 8; k++) {
            acc[k] += e * bf2f((unsigned short)e0[k]);
            acc[8 + k] += e * bf2f((unsigned short)e1[k]);
        }
        p0 = p0n; p1 = p1n; e0 = e0n; e1 = e1n;
    }

    // combine the 4 lane-groups
    lpart += __shfl_xor(lpart, 16);
    lpart += __shfl_xor(lpart, 32);
#pragma unroll
    for (int k = 0; k < 16; k++) {
        acc[k] += __shfl_xor(acc[k], 16);
        acc[k] += __shfl_xor(acc[k], 32);
    }
    float invl = 1.f / lpart;

    // lane (g,li) writes cols cb + 4g .. cb + 4g+3 (static selects)
    float4 o;
#pragma unroll
    for (int k = 0; k < 4; k++) {
        float v0 = acc[k], v1 = acc[4 + k], v2 = acc[8 + k], v3 = acc[12 + k];
        float pick = (g == 0) ? v0 : (g == 1) ? v1 : (g == 2) ? v2 : v3;
        if (k == 0) o.x = pick * invl;
        else if (k == 1) o.y = pick * invl;
        else if (k == 2) o.z = pick * invl;
        else o.w = pick * invl;
    }
    *reinterpret_cast<float4*>(orow + cb + 4 * g) = o;
    *reinterpret_cast<float4*>(orow + H + c4) =
        *reinterpret_cast<const float4*>(ent_embeds + (size_t)s[b] * H + c4);
    *reinterpret_cast<float4*>(orow + 2 * H + c4) =
        *reinterpret_cast<const float4*>(rel_embeds + (size_t)r[b] * H + c4);
}

extern "C" void kernel_launch(void* const* d_in, const int* in_sizes, int n_in,
                              void* d_out, int out_size, void* d_ws, size_t ws_size,
                              hipStream_t stream) {
    const int* s = (const int*)d_in[0];
    const int* r = (const int*)d_in[1];
    const int* nbr_ids = (const int*)d_in[2];
    const int* seg_ids = (const int*)d_in[3];
    const float* ent_embeds = (const float*)d_in[4];
    const float* rel_embeds = (const float*)d_in[5];
    const float* W_attn = (const float*)d_in[6];
    const float* b_attn = (const float*)d_in[7];
    const float* v_s = (const float*)d_in[8];
    float* out = (float*)d_out;

    int B = in_sizes[0];
    int N = in_sizes[2];
    int num_ent = in_sizes[4] / H;
    int num_seg = B * SEQ;

    char* ws = (char*)d_ws;
    unsigned short* comb = (unsigned short*)ws;                 // num_ent*512 (proj|em)
    unsigned short* Wt = comb + (size_t)num_ent * 512;          // H*3H
    unsigned short* qpartbf = Wt + (size_t)H * 3 * H;           // B*H
    int* seg_start = (int*)(qpartbf + (size_t)B * H);           // num_seg+1

    prep_Wt_kernel<<<(H * 3 * H + 255) / 256, 256, 0, stream>>>(W_attn, Wt);
    seg_start_kernel<<<(N + 255) / 256, 256, 0, stream>>>(seg_ids, seg_start, N, num_seg);

    // proj half of comb = bf16(ent) @ W0 cols; n0==0 blocks also write em half
    dim3 g1((num_ent + 63) / 64, H / 64);
    gemm_bf16_kernel<<<g1, 256, 0, stream>>>(ent_embeds, nullptr, nullptr, nullptr, nullptr,
                                             Wt, nullptr, comb, comb,
                                             num_ent, H, 0, 0, 512);
    // qpart = [s_emb|r_emb] @ W12 + b
    dim3 g2(B / 64, H / 64);
    gemm_bf16_kernel<<<g2, 256, 0, stream>>>(nullptr, s, r, ent_embeds, rel_embeds,
                                             Wt, b_attn, qpartbf, nullptr,
                                             B, 2 * H, H, 1, H);

    fused_agg_kernel<<<(num_seg + 1) / 2, 128, 0, stream>>>(
        nbr_ids, seg_start, comb, qpartbf, v_s,
        ent_embeds, rel_embeds, s, r, out, num_seg);
}